// Round 5
// baseline (408.073 us; speedup 1.0000x reference)
//
#include <hip/hip_runtime.h>
#include <hip/hip_bf16.h>

typedef __hip_bfloat16 bf16;
typedef short bf16x4v __attribute__((ext_vector_type(4)));
typedef short bf16x8v __attribute__((ext_vector_type(8)));
typedef float f32x4v __attribute__((ext_vector_type(4)));

union U8 { bf16 h[8]; bf16x8v v; };
union U4 { bf16 h[4]; bf16x4v v; };

#define MFMA(a, b, c) __builtin_amdgcn_mfma_f32_16x16x32_bf16((a), (b), (c), 0, 0, 0)

#define GLOAD_LDS16(gp, lp)                                         \
  __builtin_amdgcn_global_load_lds(                                 \
      (const __attribute__((address_space(1))) void*)(gp),          \
      (__attribute__((address_space(3))) void*)(lp), 16, 0, 0)
#define WAIT_VMCNT_8 asm volatile("s_waitcnt vmcnt(8)" ::: "memory")
#define WAIT_VMCNT_4 asm volatile("s_waitcnt vmcnt(4)" ::: "memory")
#define WAIT_VMCNT_0 asm volatile("s_waitcnt vmcnt(0)" ::: "memory")
#define WAIT_LGKM_0 asm volatile("s_waitcnt lgkmcnt(0)" ::: "memory")
#define BARRIER __builtin_amdgcn_s_barrier()

// ---------------------------------------------------------------------------
// K0 "prep": one launch doing (a) weight transpose+convert WT=[4][512][512]
// (+ fragment-packed Wpf for z==3), and (b) X f32->bf16 conversion.
// Blocks [0,1024): weights (z = bx>>8, 32x32 tile). Blocks [1024,2048): X.
// ---------------------------------------------------------------------------
__global__ __launch_bounds__(1024) void prep(
    const float* __restrict__ Wq, const float* __restrict__ Wk,
    const float* __restrict__ Wv, const float* __restrict__ Wp,
    const float* __restrict__ x, bf16* __restrict__ WT,
    bf16* __restrict__ Wpf, bf16* __restrict__ Xb) {
  const int bx = blockIdx.x;
  if (bx < 1024) {
    __shared__ float t[32][33];
    const float* srcs[4] = {Wq, Wk, Wv, Wp};
    const int z = bx >> 8, rem = bx & 255;
    const int k0 = (rem >> 4) * 32, n0 = (rem & 15) * 32;
    const int ty = threadIdx.x >> 5, tx = threadIdx.x & 31;
    t[ty][tx] = srcs[z][(size_t)(k0 + ty) * 512 + n0 + tx];
    __syncthreads();
    float v = t[tx][ty];  // = W[k0+tx][n0+ty]
    WT[((size_t)z * 512 + n0 + ty) * 512 + k0 + tx] = (bf16)v;
    if (z == 3) {
      const int k = k0 + tx, d = n0 + ty;
      const int f = (d >> 4) * 16 + (k >> 5);
      const int lane = ((k >> 3) & 3) * 16 + (d & 15);
      Wpf[(size_t)f * 512 + lane * 8 + (k & 7)] = (bf16)v;
    }
  } else {
    size_t base = ((size_t)(bx - 1024) * 1024 + threadIdx.x) * 8;
    f32x4v a = *(const f32x4v*)(x + base);
    f32x4v b = *(const f32x4v*)(x + base + 4);
    U8 u;
#pragma unroll
    for (int e = 0; e < 4; e++) {
      u.h[e] = (bf16)a[e];
      u.h[4 + e] = (bf16)b[e];
    }
    *(bf16x8v*)(Xb + base) = u.v;
  }
}

// ---------------------------------------------------------------------------
// K1 v3: QKV projection GEMM, m97-style global_load_lds staging.
// OUT[m][n] = sum_k Xb[m][k]*WT[n][k] + bias[n]. 128x128 tile, BK=32,
// 256 threads (4 waves, 2x2 of 64x64). 3-slot LDS ring, XOR segment swizzle,
// counted vmcnt(4), one barrier per K-step. 48 KB LDS -> 3 blocks/CU.
// blockIdx.z selects Q / K / V. V is written FRAGMENT-PACKED (see round 1).
// ---------------------------------------------------------------------------
__global__ __launch_bounds__(256) void qkv_gemm(
    const bf16* __restrict__ Xb, const bf16* __restrict__ WTall,
    const float* __restrict__ bq, const float* __restrict__ bk,
    const float* __restrict__ bv,
    bf16* __restrict__ Q, bf16* __restrict__ Km, bf16* __restrict__ Vf) {
  __shared__ __align__(16) bf16 ring[3][8192];  // 3 x 16 KB
  const int which = blockIdx.z;
  const bf16* Wt = WTall + (size_t)which * 512 * 512;
  const float* bias = (which == 0) ? bq : (which == 1 ? bk : bv);
  const int n0 = blockIdx.x * 128;
  const int m0 = blockIdx.y * 128;
  const int tid = threadIdx.x;
  const int lane = tid & 63, w = tid >> 6;
  const int wr = w >> 1, wc = w & 1;
  const int quad = lane >> 4, l15 = lane & 15;

  f32x4v acc[4][4];
#pragma unroll
  for (int i = 0; i < 4; i++)
#pragma unroll
    for (int j = 0; j < 4; j++) acc[i][j] = (f32x4v){0.f, 0.f, 0.f, 0.f};

  // staging geometry: per wave, load i covers rows (i*4+w)*16 .. +16
  // (1 KB = 16 rows x 64 B); lane l -> row +(l>>2), seg l&3.
  const int segg = ((lane & 3) ^ ((lane >> 3) & 3)) * 8;  // pre-swizzled, elems
  const bf16* xb0 = Xb + (size_t)m0 * 512;
  const bf16* wb0 = Wt + (size_t)n0 * 512;

#define QKV_STAGE(kt_, slot_)                                                 \
  {                                                                           \
    const int k0_ = (kt_) * 32;                                               \
    char* sb_ = (char*)ring[(slot_)];                                         \
    _Pragma("unroll") for (int i = 0; i < 2; i++) {                           \
      const int R_ = (i * 4 + w) * 16 + (lane >> 2);                          \
      GLOAD_LDS16(xb0 + (size_t)R_ * 512 + k0_ + segg,                        \
                  sb_ + (i * 4 + w) * 1024);                                  \
      GLOAD_LDS16(wb0 + (size_t)R_ * 512 + k0_ + segg,                        \
                  sb_ + 8192 + (i * 4 + w) * 1024);                           \
    }                                                                         \
  }

  QKV_STAGE(0, 0);
  QKV_STAGE(1, 1);

  const int sxa = ((l15 >> 1) & 3);  // read-side seg XOR
  for (int kt = 0; kt < 16; ++kt) {
    WAIT_VMCNT_4;  // stage kt complete (stage kt+1 may stay in flight)
    WAIT_LGKM_0;
    BARRIER;       // publish slot kt%3; license re-stage of slot (kt+2)%3
    const int nk = (kt + 2 > 15) ? 15 : (kt + 2);
    QKV_STAGE(nk, (kt + 2) % 3);
    const char* As_ = (const char*)ring[kt % 3];
    bf16x8v a[4], b[4];
#pragma unroll
    for (int i = 0; i < 4; i++)
      a[i] = *(const bf16x8v*)(As_ + (wr * 64 + i * 16 + l15) * 64 +
                               ((quad ^ sxa) << 4));
#pragma unroll
    for (int j = 0; j < 4; j++)
      b[j] = *(const bf16x8v*)(As_ + 8192 + (wc * 64 + j * 16 + l15) * 64 +
                               ((quad ^ sxa) << 4));
#pragma unroll
    for (int i = 0; i < 4; i++)
#pragma unroll
      for (int j = 0; j < 4; j++) acc[i][j] = MFMA(a[i], b[j], acc[i][j]);
  }
#undef QKV_STAGE

#pragma unroll
  for (int j = 0; j < 4; j++) {
    int col = n0 + wc * 64 + j * 16 + l15;
    float bv_ = bias[col];
#pragma unroll
    for (int i = 0; i < 4; i++) {
      if (which == 2) {
        int row0 = m0 + wr * 64 + i * 16 + quad * 4;  // s for r=0; r adds +1..3
        int b_ = row0 >> 11, s_ = row0 & 2047;
        size_t fi = ((((size_t)b_ * 32 + (col >> 4)) * 64 + (s_ >> 5)) * 4 +
                     ((s_ >> 3) & 3)) * 128 +
                    (size_t)(col & 15) * 8 + (s_ & 7);
        U4 p4;
#pragma unroll
        for (int r = 0; r < 4; r++) p4.h[r] = (bf16)(acc[i][j][r] + bv_);
        *(bf16x4v*)(Vf + fi) = p4.v;  // 8-B aligned (s_&7 in {0,4})
      } else {
#pragma unroll
        for (int r = 0; r < 4; r++) {
          int row = m0 + wr * 64 + i * 16 + quad * 4 + r;
          float v = acc[i][j][r] + bv_;
          if (which == 0) Q[(size_t)row * 512 + col] = (bf16)v;
          else            Km[(size_t)row * 512 + col] = (bf16)v;
        }
      }
    }
  }
}

// ---------------------------------------------------------------------------
// attn phase-1 K staging: chunk c = (stile = c&31, dhalf = c>>5) is
// K[stile*64 .. +64][dhalf*256 .. +256] = 32 KB into a 4-slot ring.
// LDS linear (rows of 512 B); bank swizzle seg ^= row&7 applied via the
// per-lane pre-swizzled GLOBAL source (both-sides rule).
// Per wave: 4 loads, each 1 KB = 2 rows; load i covers rows (i*8+w)*2 .. +2.
// ---------------------------------------------------------------------------
__device__ __forceinline__ void stage_k2(const bf16* __restrict__ Kb, char* ring,
                                         int c, int slot, int w, int lane) {
  const int stile = c & 31, dhalf = c >> 5;
  const bf16* gb = Kb + (size_t)stile * (64 * 512) + dhalf * 256;
  char* sb = ring + slot * 32768;
#pragma unroll
  for (int i = 0; i < 4; i++) {
    const int rp = (i * 8 + w) * 2;
    const int R = rp + (lane >> 5);
    const int seg = (lane & 31) ^ (R & 7);
    GLOAD_LDS16(gb + (size_t)R * 512 + seg * 8, sb + rp * 512);
  }
}

// ---------------------------------------------------------------------------
// K2 v7: fused attention + out-projection + residual + LayerNorm.
// One block = one (batch, 32-row Q-tile), 512 thr, batch XCD-pinned.
// 1 block/CU (unified-reg cap ~252); all latency must hide in-pipeline.
// Phase 1: 64 chunks of 32 KB, 4-SLOT ring, stage-ahead 3, vmcnt(8)
//          -> TWO full chunk-times of latency cover. 1 barrier/chunk.
// Phase 2: softmax stats only (attn write deferred to phase 3).
// Phase 3: per stile: V(st+1) frags issued BEFORE the barrier (barrier-wait
//          + P-read cover); normalize + attn f32 store + Pst double-buffer
//          write after; one barrier per stile.
// Epilogue: O-tile -> LDS (swizzled, ring reused); out = O @ Wp (ping-pong
//          Wpf prefetch) + bp + x residual; LayerNorm; write Y f32.
// ---------------------------------------------------------------------------
__global__ __launch_bounds__(512, 2) void attn_kernel(
    const bf16* __restrict__ Q, const bf16* __restrict__ Km,
    const bf16* __restrict__ Vf, float* __restrict__ attn,
    const bf16* __restrict__ Wpf, const float* __restrict__ bp,
    const float* __restrict__ x, const float* __restrict__ gamma,
    const float* __restrict__ beta, float* __restrict__ Y) {
  __shared__ __align__(16) char smem[131072];       // 4x32 KB ring / Os (epilogue)
  __shared__ float red[512];                        // 2 KB
  __shared__ __align__(16) bf16 Pst[2][32][72];     // 9.2 KB, 144-B rows

  const int b = blockIdx.x & 7;
  const int q0 = (blockIdx.x >> 3) << 5;
  const int tid = threadIdx.x, lane = tid & 63, w = tid >> 6;
  const int rg = w >> 2, cgi = w & 3;
  const int quad = lane >> 4, l15 = lane & 15;
  const float scale = 0.044194173824159216f;  // 1/sqrt(512)

  const bf16* Kb = Km + (size_t)b * 2048 * 512;

  // Q fragments direct from global (one-time; 16 x 16B per lane)
  bf16x8v a[16];
  {
    const bf16* qrow = Q + ((size_t)b * 2048 + q0 + rg * 16 + l15) * 512 + quad * 8;
#pragma unroll
    for (int kk = 0; kk < 16; kk++) a[kk] = *(const bf16x8v*)(qrow + kk * 32);
  }

  f32x4v acc[32];
#pragma unroll
  for (int st = 0; st < 32; st++) acc[st] = (f32x4v){0.f, 0.f, 0.f, 0.f};

  // ---- phase 1: S = Q K^T ----
  stage_k2(Kb, smem, 0, 0, w, lane);
  stage_k2(Kb, smem, 1, 1, w, lane);
  stage_k2(Kb, smem, 2, 2, w, lane);
  WAIT_VMCNT_0;  // drain Q loads + prologue stages (removes issue-order deps)
  BARRIER;

  const int sx7 = l15 & 7;
#pragma unroll
  for (int c = 0; c < 64; ++c) {
    WAIT_VMCNT_8;   // chunk c's stage complete (c+1, c+2 may stay in flight)
    WAIT_LGKM_0;    // my prior ds_reads retired (slot about to be re-staged)
    BARRIER;        // publish chunk c; license re-staging slot (c+3)&3
    const int cn = (c + 3 > 63) ? 63 : (c + 3);  // clamped re-stage: uniform vmcnt
    stage_k2(Kb, smem, cn, (c + 3) & 3, w, lane);
    const int stile = c & 31, dhalf = c >> 5;
    const char* kb = (const char*)smem + (c & 3) * 32768 + (cgi * 16 + l15) * 512;
    f32x4v t = acc[stile];
#pragma unroll
    for (int kk = 0; kk < 8; kk++) {
      bf16x8v bfr = *(const bf16x8v*)(kb + (((kk * 4 + quad) ^ sx7) << 4));
      t = MFMA(a[dhalf * 8 + kk], bfr, t);
    }
    acc[stile] = t;
  }
  WAIT_VMCNT_0;  // drain stray clamped stages (write dead ring slots only)
  BARRIER;

#pragma unroll
  for (int st = 0; st < 32; st++) acc[st] = acc[st] * scale;

  // ---- phase 2: softmax stats (l15 shuffles + cross-wave LDS reduce) ----
  float m[4], l[4];
#pragma unroll
  for (int r = 0; r < 4; r++) m[r] = -1e30f;
#pragma unroll
  for (int st = 0; st < 32; st++)
#pragma unroll
    for (int r = 0; r < 4; r++) m[r] = fmaxf(m[r], acc[st][r]);
#pragma unroll
  for (int off = 1; off < 16; off <<= 1)
#pragma unroll
    for (int r = 0; r < 4; r++) m[r] = fmaxf(m[r], __shfl_xor(m[r], off, 64));
  if (l15 == 0)
#pragma unroll
    for (int r = 0; r < 4; r++) red[rg * 64 + cgi * 16 + quad * 4 + r] = m[r];
  __syncthreads();
#pragma unroll
  for (int r = 0; r < 4; r++) {
    int row = rg * 64 + quad * 4 + r;
    float mm = red[row];
    for (int ww = 1; ww < 4; ww++) mm = fmaxf(mm, red[row + ww * 16]);
    m[r] = mm;
  }
#pragma unroll
  for (int r = 0; r < 4; r++) l[r] = 0.f;
#pragma unroll
  for (int st = 0; st < 32; st++)
#pragma unroll
    for (int r = 0; r < 4; r++) {
      float p = __expf(acc[st][r] - m[r]);
      acc[st][r] = p;   // unnormalized exp kept in regs
      l[r] += p;
    }
#pragma unroll
  for (int off = 1; off < 16; off <<= 1)
#pragma unroll
    for (int r = 0; r < 4; r++) l[r] += __shfl_xor(l[r], off, 64);
  if (l15 == 0)
#pragma unroll
    for (int r = 0; r < 4; r++) red[256 + rg * 64 + cgi * 16 + quad * 4 + r] = l[r];
  __syncthreads();
#pragma unroll
  for (int r = 0; r < 4; r++) {
    int row = 256 + rg * 64 + quad * 4 + r;
    float s_ = 0.f;
    for (int ww = 0; ww < 4; ww++) s_ += red[row + ww * 16];
    l[r] = 1.0f / s_;
  }

  // ---- phase 3: O = P V with normalize+attn-store interleaved ----
  f32x4v acc2[2][4];
#pragma unroll
  for (int hg = 0; hg < 2; hg++)
#pragma unroll
    for (int j = 0; j < 4; j++) acc2[hg][j] = (f32x4v){0.f, 0.f, 0.f, 0.f};
  const bf16* Vfb = Vf + (size_t)b * (1 << 20);  // 2 MB/batch, frag-packed
  const int w4 = w * 4;
  const int lane8 = lane * 8;
  float* attn_base = attn + ((size_t)(b * 2048) + q0 + rg * 16 + quad * 4) * 2048 +
                     cgi * 16 + l15;

  // prologue: normalize st=0, store attn row-chunk 0, write Pst[0], preload V(0)
#pragma unroll
  for (int r = 0; r < 4; r++) {
    float p = acc[0][r] * l[r];
    attn_base[(size_t)r * 2048] = p;
    Pst[0][rg * 16 + quad * 4 + r][cgi * 16 + l15] = (bf16)p;
  }
  bf16x8v vfp[2][2][4];
#pragma unroll
  for (int ss = 0; ss < 2; ss++)
#pragma unroll
    for (int j = 0; j < 4; j++)
      vfp[0][ss][j] = *(const bf16x8v*)(Vfb + ((size_t)(w4 + j) * 64 + ss) * 512 + lane8);

#pragma unroll
  for (int st = 0; st < 32; ++st) {
    const int cur = st & 1;
    // ping-pong V prefetch for st+1 issued BEFORE the barrier: cover =
    // barrier-wait + P reads + MFMA block of this stile.
    if (st < 31) {
#pragma unroll
      for (int ss = 0; ss < 2; ss++)
#pragma unroll
        for (int j = 0; j < 4; j++)
          vfp[cur ^ 1][ss][j] = *(const bf16x8v*)(
              Vfb + ((size_t)(w4 + j) * 64 + (st + 1) * 2 + ss) * 512 + lane8);
    }
    WAIT_LGKM_0;  // my Pst writes (st) and prior reads (st-1) retired
    BARRIER;      // publish P(st); licenses overwrite of buf cur^1
    const char* pb = (const char*)Pst[cur];
    bf16x8v a0[2], a1[2];
#pragma unroll
    for (int ss = 0; ss < 2; ss++) {
      a0[ss] = *(const bf16x8v*)(pb + l15 * 144 + ss * 64 + quad * 16);
      a1[ss] = *(const bf16x8v*)(pb + (16 + l15) * 144 + ss * 64 + quad * 16);
    }
    if (st < 31) {
      // normalize + attn store + Pst write for st+1 (spreads the 134 MB write)
#pragma unroll
      for (int r = 0; r < 4; r++) {
        float p = acc[st + 1][r] * l[r];
        attn_base[(size_t)r * 2048 + (st + 1) * 64] = p;
        Pst[cur ^ 1][rg * 16 + quad * 4 + r][cgi * 16 + l15] = (bf16)p;
      }
    }
#pragma unroll
    for (int ss = 0; ss < 2; ss++)
#pragma unroll
      for (int j = 0; j < 4; j++) {
        acc2[0][j] = MFMA(a0[ss], vfp[cur][ss][j], acc2[0][j]);
        acc2[1][j] = MFMA(a1[ss], vfp[cur][ss][j], acc2[1][j]);
      }
  }

  // ---- epilogue A: stage O-tile (bf16, XOR-swizzled) into Os (dead ring);
  //      prefetch first Wpf frags before the barrier ----
  bf16* Os = (bf16*)smem;  // 32 KB: 32 rows x 1024 B
#pragma unroll
  for (int hg = 0; hg < 2; hg++)
#pragma unroll
    for (int j = 0; j < 4; j++) {
      const int colb = (w * 64 + j * 16 + l15) * 2;
#pragma unroll
      for (int r = 0; r < 4; r++) {
        const int row = hg * 16 + quad * 4 + r;
        *(bf16*)((char*)Os + row * 1024 + (colb ^ ((row & 7) << 4))) =
            (bf16)acc2[hg][j][r];
      }
    }
  bf16x8v bfq[2][4];
#pragma unroll
  for (int j2 = 0; j2 < 4; j2++)
    bfq[0][j2] = *(const bf16x8v*)(Wpf + ((size_t)(w4 + j2) * 16 + 0) * 512 + lane8);
  WAIT_LGKM_0;
  BARRIER;

  // ---- epilogue B: out = O @ Wp (+bp) + x residual, LayerNorm, write Y ----
  f32x4v pacc[2][4];
#pragma unroll
  for (int rt = 0; rt < 2; rt++)
#pragma unroll
    for (int j2 = 0; j2 < 4; j2++) pacc[rt][j2] = (f32x4v){0.f, 0.f, 0.f, 0.f};
  const int sx7e = l15 & 7;
#pragma unroll
  for (int kk = 0; kk < 16; ++kk) {
    if (kk < 15) {
#pragma unroll
      for (int j2 = 0; j2 < 4; j2++)
        bfq[(kk + 1) & 1][j2] =
            *(const bf16x8v*)(Wpf + ((size_t)(w4 + j2) * 16 + kk + 1) * 512 + lane8);
    }
    const int swz = (((kk * 4 + quad) ^ sx7e) << 4);
    bf16x8v af0 = *(const bf16x8v*)((const char*)Os + l15 * 1024 + swz);
    bf16x8v af1 = *(const bf16x8v*)((const char*)Os + (16 + l15) * 1024 + swz);
#pragma unroll
    for (int j2 = 0; j2 < 4; j2++) {
      pacc[0][j2] = MFMA(af0, bfq[kk & 1][j2], pacc[0][j2]);
      pacc[1][j2] = MFMA(af1, bfq[kk & 1][j2], pacc[1][j2]);
    }
  }

  const float* xr = x + ((size_t)b * 2048 + q0) * 512;
  float s1[2][4], s2[2][4];
#pragma unroll
  for (int rt = 0; rt < 2; rt++)
#pragma unroll
    for (int r = 0; r < 4; r++) { s1[rt][r] = 0.f; s2[rt][r] = 0.f; }
#pragma unroll
  for (int rt = 0; rt < 2; rt++)
#pragma unroll
    for (int j2 = 0; j2 < 4; j2++) {
      const int col = w * 64 + j2 * 16 + l15;
      const float bpv = bp[col];
#pragma unroll
      for (int r = 0; r < 4; r++) {
        const int row = rt * 16 + quad * 4 + r;
        float v = pacc[rt][j2][r] + bpv + xr[(size_t)row * 512 + col];
        pacc[rt][j2][r] = v;
        s1[rt][r] += v;
        s2[rt][r] += v * v;
      }
    }
#pragma unroll
  for (int off = 1; off < 16; off <<= 1)
#pragma unroll
    for (int rt = 0; rt < 2; rt++)
#pragma unroll
      for (int r = 0; r < 4; r++) {
        s1[rt][r] += __shfl_xor(s1[rt][r], off, 64);
        s2[rt][r] += __shfl_xor(s2[rt][r], off, 64);
      }
  if (l15 == 0)
#pragma unroll
    for (int rt = 0; rt < 2; rt++)
#pragma unroll
      for (int r = 0; r < 4; r++) {
        red[w * 32 + rt * 16 + quad * 4 + r] = s1[rt][r];
        red[256 + w * 32 + rt * 16 + quad * 4 + r] = s2[rt][r];
      }
  __syncthreads();
  float mu[2][4], rs[2][4];
#pragma unroll
  for (int rt = 0; rt < 2; rt++)
#pragma unroll
    for (int r = 0; r < 4; r++) {
      const int row = rt * 16 + quad * 4 + r;
      float a1 = 0.f, a2 = 0.f;
      for (int ww = 0; ww < 8; ww++) {
        a1 += red[ww * 32 + row];
        a2 += red[256 + ww * 32 + row];
      }
      mu[rt][r] = a1 * (1.0f / 512.0f);
      float var = a2 * (1.0f / 512.0f) - mu[rt][r] * mu[rt][r];
      rs[rt][r] = rsqrtf(var + 1e-5f);
    }
  float* Yr = Y + ((size_t)b * 2048 + q0) * 512;
#pragma unroll
  for (int rt = 0; rt < 2; rt++)
#pragma unroll
    for (int j2 = 0; j2 < 4; j2++) {
      const int col = w * 64 + j2 * 16 + l15;
      const float g = gamma[col], be = beta[col];
#pragma unroll
      for (int r = 0; r < 4; r++) {
        const int row = rt * 16 + quad * 4 + r;
        Yr[(size_t)row * 512 + col] = (pacc[rt][j2][r] - mu[rt][r]) * rs[rt][r] * g + be;
      }
    }
}

// ---------------------------------------------------------------------------
extern "C" void kernel_launch(void* const* d_in, const int* in_sizes, int n_in,
                              void* d_out, int out_size, void* d_ws, size_t ws_size,
                              hipStream_t stream) {
  const float* x = (const float*)d_in[0];
  const float* Wq = (const float*)d_in[1];
  const float* bq = (const float*)d_in[2];
  const float* Wk = (const float*)d_in[3];
  const float* bk = (const float*)d_in[4];
  const float* Wv = (const float*)d_in[5];
  const float* bv = (const float*)d_in[6];
  const float* Wp = (const float*)d_in[7];
  const float* bp = (const float*)d_in[8];
  const float* gamma = (const float*)d_in[9];
  const float* beta = (const float*)d_in[10];

  char* ws = (char*)d_ws;
  bf16* WT = (bf16*)ws;                                      // 2 MB
  size_t off = 4ull * 512 * 512 * 2;
  bf16* Qd = (bf16*)(ws + off); off += 16384ull * 512 * 2;   // 16 MB
  bf16* Kd = (bf16*)(ws + off); off += 16384ull * 512 * 2;   // 16 MB
  bf16* Vfd = (bf16*)(ws + off); off += 16384ull * 512 * 2;  // 16 MB (frag-packed)
  bf16* Wpf = (bf16*)(ws + off); off += 512ull * 1024;       // 0.5 MB (frag-packed Wp)

  float* Y = (float*)d_out;                     // f32 [8][2048][512]
  float* attn = Y + 8ull * 2048 * 512;          // f32 [8][2048][2048]
  bf16* Xb = (bf16*)d_out;  // bf16 X parked in Y region (consumed by qkv_gemm)

  hipLaunchKernelGGL(prep, dim3(2048), dim3(1024), 0, stream,
                     Wq, Wk, Wv, Wp, x, WT, Wpf, Xb);
  hipLaunchKernelGGL(qkv_gemm, dim3(4, 128, 3), dim3(256), 0, stream,
                     Xb, WT, bq, bk, bv, Qd, Kd, Vfd);
  hipLaunchKernelGGL(attn_kernel, dim3(512), dim3(512), 0, stream,
                     Qd, Kd, Vfd, attn, Wpf, bp, x, gamma, beta, Y);
}

// Round 6
// 377.654 us; speedup vs baseline: 1.0805x; 1.0805x over previous
//
#include <hip/hip_runtime.h>
#include <hip/hip_bf16.h>

typedef __hip_bfloat16 bf16;
typedef short bf16x4v __attribute__((ext_vector_type(4)));
typedef short bf16x8v __attribute__((ext_vector_type(8)));
typedef float f32x4v __attribute__((ext_vector_type(4)));

union U8 { bf16 h[8]; bf16x8v v; };
union U4 { bf16 h[4]; bf16x4v v; };

#define MFMA(a, b, c) __builtin_amdgcn_mfma_f32_16x16x32_bf16((a), (b), (c), 0, 0, 0)

#define GLOAD_LDS16(gp, lp)                                         \
  __builtin_amdgcn_global_load_lds(                                 \
      (const __attribute__((address_space(1))) void*)(gp),          \
      (__attribute__((address_space(3))) void*)(lp), 16, 0, 0)
#define WAIT_VMCNT_4 asm volatile("s_waitcnt vmcnt(4)" ::: "memory")
#define WAIT_VMCNT_0 asm volatile("s_waitcnt vmcnt(0)" ::: "memory")
#define WAIT_LGKM_0 asm volatile("s_waitcnt lgkmcnt(0)" ::: "memory")
#define BARRIER __builtin_amdgcn_s_barrier()

// ---------------------------------------------------------------------------
// K0 "prep": one launch doing (a) weight transpose+convert WT=[4][512][512]
// (+ fragment-packed Wpf for z==3), and (b) X f32->bf16 conversion.
// Blocks [0,1024): weights (z = bx>>8, 32x32 tile). Blocks [1024,2048): X.
// ---------------------------------------------------------------------------
__global__ __launch_bounds__(1024) void prep(
    const float* __restrict__ Wq, const float* __restrict__ Wk,
    const float* __restrict__ Wv, const float* __restrict__ Wp,
    const float* __restrict__ x, bf16* __restrict__ WT,
    bf16* __restrict__ Wpf, bf16* __restrict__ Xb) {
  const int bx = blockIdx.x;
  if (bx < 1024) {
    __shared__ float t[32][33];
    const float* srcs[4] = {Wq, Wk, Wv, Wp};
    const int z = bx >> 8, rem = bx & 255;
    const int k0 = (rem >> 4) * 32, n0 = (rem & 15) * 32;
    const int ty = threadIdx.x >> 5, tx = threadIdx.x & 31;
    t[ty][tx] = srcs[z][(size_t)(k0 + ty) * 512 + n0 + tx];
    __syncthreads();
    float v = t[tx][ty];  // = W[k0+tx][n0+ty]
    WT[((size_t)z * 512 + n0 + ty) * 512 + k0 + tx] = (bf16)v;
    if (z == 3) {
      const int k = k0 + tx, d = n0 + ty;
      const int f = (d >> 4) * 16 + (k >> 5);
      const int lane = ((k >> 3) & 3) * 16 + (d & 15);
      Wpf[(size_t)f * 512 + lane * 8 + (k & 7)] = (bf16)v;
    }
  } else {
    size_t base = ((size_t)(bx - 1024) * 1024 + threadIdx.x) * 8;
    f32x4v a = *(const f32x4v*)(x + base);
    f32x4v b = *(const f32x4v*)(x + base + 4);
    U8 u;
#pragma unroll
    for (int e = 0; e < 4; e++) {
      u.h[e] = (bf16)a[e];
      u.h[4 + e] = (bf16)b[e];
    }
    *(bf16x8v*)(Xb + base) = u.v;
  }
}

// ---------------------------------------------------------------------------
// K1 v4: QKV projection GEMM, m97-style global_load_lds staging.
// OUT[m][n] = sum_k Xb[m][k]*WT[n][k] + bias[n]. 128x128 tile, BK=32,
// 256 threads (4 waves, 2x2 of 64x64). 3-slot LDS ring, XOR segment swizzle
// (both-sides), counted vmcnt(4), one barrier per K-step, proper epilogue
// (no clamped re-stage waste). 48 KB LDS -> 3 blocks/CU.
// blockIdx.z selects Q / K / V.
// K is written FRAGMENT-PACKED (Kf) for the attn QK^T stream:
//   frag fid = (s>>4)*16 + (h>>5); lane = (s&15) + ((h>>3)&3)*16; e = h&7
//   Kf[b][fid*512 + lane*8 + e] = K[s][h]   (1 KB per frag, per batch 2 MB)
// V is written FRAGMENT-PACKED (Vf, round-1 layout).
// ---------------------------------------------------------------------------
__global__ __launch_bounds__(256) void qkv_gemm(
    const bf16* __restrict__ Xb, const bf16* __restrict__ WTall,
    const float* __restrict__ bq, const float* __restrict__ bk,
    const float* __restrict__ bv,
    bf16* __restrict__ Q, bf16* __restrict__ Kf, bf16* __restrict__ Vf) {
  __shared__ __align__(16) bf16 ring[3][8192];  // 3 x 16 KB
  const int which = blockIdx.z;
  const bf16* Wt = WTall + (size_t)which * 512 * 512;
  const float* bias = (which == 0) ? bq : (which == 1 ? bk : bv);
  const int n0 = blockIdx.x * 128;
  const int m0 = blockIdx.y * 128;
  const int tid = threadIdx.x;
  const int lane = tid & 63, w = tid >> 6;
  const int wr = w >> 1, wc = w & 1;
  const int quad = lane >> 4, l15 = lane & 15;

  f32x4v acc[4][4];
#pragma unroll
  for (int i = 0; i < 4; i++)
#pragma unroll
    for (int j = 0; j < 4; j++) acc[i][j] = (f32x4v){0.f, 0.f, 0.f, 0.f};

  // staging geometry: per wave, load i covers rows (i*4+w)*16 .. +16
  // (1 KB = 16 rows x 64 B); lane l -> row +(l>>2), seg l&3.
  const int segg = ((lane & 3) ^ ((lane >> 3) & 3)) * 8;  // pre-swizzled, elems
  const bf16* xb0 = Xb + (size_t)m0 * 512;
  const bf16* wb0 = Wt + (size_t)n0 * 512;

#define QKV_STAGE(kt_, slot_)                                                 \
  {                                                                           \
    const int k0_ = (kt_) * 32;                                               \
    char* sb_ = (char*)ring[(slot_)];                                         \
    _Pragma("unroll") for (int i = 0; i < 2; i++) {                           \
      const int R_ = (i * 4 + w) * 16 + (lane >> 2);                          \
      GLOAD_LDS16(xb0 + (size_t)R_ * 512 + k0_ + segg,                        \
                  sb_ + (i * 4 + w) * 1024);                                  \
      GLOAD_LDS16(wb0 + (size_t)R_ * 512 + k0_ + segg,                        \
                  sb_ + 8192 + (i * 4 + w) * 1024);                           \
    }                                                                         \
  }

  QKV_STAGE(0, 0);
  QKV_STAGE(1, 1);

  const int sxa = ((l15 >> 1) & 3);  // read-side seg XOR
#pragma unroll
  for (int kt = 0; kt < 16; ++kt) {
    if (kt < 15) { WAIT_VMCNT_4; } else { WAIT_VMCNT_0; }
    WAIT_LGKM_0;
    BARRIER;       // publish slot kt%3; license re-stage of slot (kt+2)%3
    if (kt < 14) QKV_STAGE(kt + 2, (kt + 2) % 3);
    const char* As_ = (const char*)ring[kt % 3];
    bf16x8v a[4], b[4];
#pragma unroll
    for (int i = 0; i < 4; i++)
      a[i] = *(const bf16x8v*)(As_ + (wr * 64 + i * 16 + l15) * 64 +
                               ((quad ^ sxa) << 4));
#pragma unroll
    for (int j = 0; j < 4; j++)
      b[j] = *(const bf16x8v*)(As_ + 8192 + (wc * 64 + j * 16 + l15) * 64 +
                               ((quad ^ sxa) << 4));
#pragma unroll
    for (int i = 0; i < 4; i++)
#pragma unroll
      for (int j = 0; j < 4; j++) acc[i][j] = MFMA(a[i], b[j], acc[i][j]);
  }
#undef QKV_STAGE

#pragma unroll
  for (int j = 0; j < 4; j++) {
    int col = n0 + wc * 64 + j * 16 + l15;
    float bv_ = bias[col];
#pragma unroll
    for (int i = 0; i < 4; i++) {
      int row0 = m0 + wr * 64 + i * 16 + quad * 4;  // s for r=0; r adds +1..3
      int b_ = row0 >> 11, s0 = row0 & 2047;
      if (which == 2) {
        size_t fi = ((((size_t)b_ * 32 + (col >> 4)) * 64 + (s0 >> 5)) * 4 +
                     ((s0 >> 3) & 3)) * 128 +
                    (size_t)(col & 15) * 8 + (s0 & 7);
        U4 p4;
#pragma unroll
        for (int r = 0; r < 4; r++) p4.h[r] = (bf16)(acc[i][j][r] + bv_);
        *(bf16x4v*)(Vf + fi) = p4.v;  // 8-B aligned (s0&7 in {0,4})
      } else if (which == 1) {
        // fragment-packed K: fid=(s>>4)*16+(h>>5); lane=(s&15)+((h>>3)&3)*16
        bf16* kfo = Kf + ((size_t)b_ << 20) + (size_t)(col >> 5) * 512 +
                    (size_t)(((col >> 3) & 3) << 4) * 8 + (col & 7);
#pragma unroll
        for (int r = 0; r < 4; r++) {
          int s_ = s0 + r;  // quad*4+r stays within the 16-block (no carry)
          kfo[((size_t)(s_ >> 4) * 16) * 512 + (size_t)(s_ & 15) * 8] =
              (bf16)(acc[i][j][r] + bv_);
        }
      } else {
#pragma unroll
        for (int r = 0; r < 4; r++) {
          int row = row0 + r;
          Q[(size_t)(b_ * 2048 + s0 + r) * 512 + col] = (bf16)(acc[i][j][r] + bv_);
          (void)row;
        }
      }
    }
  }
}

// ---------------------------------------------------------------------------
// K2 v8: fused attention + out-projection + residual + LayerNorm.
// One block = one (batch, 32-row Q-tile), 512 thr, batch XCD-pinned.
// 1 block/CU (unified-reg cap ~252); all latency hidden in-register.
// Phase 1: S = Q K^T as a BARRIER-FREE register stream: K fragments are
//          pre-packed (Kf) so each wave's B-operand is a contiguous 1 KB
//          load; ping-pong kfp[2][8] prefetch (distance = 1 stile-group,
//          8 loads in flight, BW-paced). Q frags loaded per-half (aq[8]),
//          halving their live range. NO LDS, NO barriers in phase 1.
// Phase 2: softmax stats only (attn write deferred to phase 3).
// Phase 3: per stile: barrier; P reads; normalize + attn f32 store + Pst
//          double-buffer write for st+1; V ping-pong prefetch (R4-proven
//          placement); 16 MFMA. One barrier per stile.
// Epilogue: O-tile -> LDS Os (swizzled); out = O @ Wp (ping-pong Wpf
//          prefetch) + bp + x residual; LayerNorm; write Y f32.
// ---------------------------------------------------------------------------
__global__ __launch_bounds__(512, 2) void attn_kernel(
    const bf16* __restrict__ Q, const bf16* __restrict__ Kf,
    const bf16* __restrict__ Vf, float* __restrict__ attn,
    const bf16* __restrict__ Wpf, const float* __restrict__ bp,
    const float* __restrict__ x, const float* __restrict__ gamma,
    const float* __restrict__ beta, float* __restrict__ Y) {
  __shared__ __align__(16) bf16 Os[32][512];        // 32 KB (epilogue O staging)
  __shared__ float red[512];                        // 2 KB
  __shared__ __align__(16) bf16 Pst[2][32][72];     // 9.2 KB, 144-B rows

  const int b = blockIdx.x & 7;
  const int q0 = (blockIdx.x >> 3) << 5;
  const int tid = threadIdx.x, lane = tid & 63, w = tid >> 6;
  const int rg = w >> 2, cgi = w & 3;
  const int quad = lane >> 4, l15 = lane & 15;
  const int lane8 = lane * 8;
  const float scale = 0.044194173824159216f;  // 1/sqrt(512)

  f32x4v acc[32];
#pragma unroll
  for (int st = 0; st < 32; st++) acc[st] = (f32x4v){0.f, 0.f, 0.f, 0.f};

  // ---- phase 1: S = Q K^T, barrier-free fragment streaming ----
  // frag id for (st, cgi, kk) = st*64 + cgi*16 + kk (1 KB each)
  const bf16* Kfb = Kf + ((size_t)b << 20);
  const bf16* qrow = Q + ((size_t)(b * 2048) + q0 + rg * 16 + l15) * 512 + quad * 8;
  const int fbase = cgi * 16;
#pragma unroll
  for (int half = 0; half < 2; ++half) {
    bf16x8v aq[8];
#pragma unroll
    for (int q = 0; q < 8; q++)
      aq[q] = *(const bf16x8v*)(qrow + (half * 8 + q) * 32);
    bf16x8v kfp[2][8];
#pragma unroll
    for (int q = 0; q < 8; q++)
      kfp[0][q] = *(const bf16x8v*)(Kfb + (size_t)(fbase + half * 8 + q) * 512 + lane8);
#pragma unroll
    for (int st = 0; st < 32; ++st) {
      const int cur = st & 1;
      if (st < 31) {
#pragma unroll
        for (int q = 0; q < 8; q++)
          kfp[cur ^ 1][q] = *(const bf16x8v*)(
              Kfb + (size_t)((st + 1) * 64 + fbase + half * 8 + q) * 512 + lane8);
      }
      f32x4v t = acc[st];
#pragma unroll
      for (int q = 0; q < 8; q++) t = MFMA(aq[q], kfp[cur][q], t);
      acc[st] = t;
    }
  }

#pragma unroll
  for (int st = 0; st < 32; st++) acc[st] = acc[st] * scale;

  // ---- phase 2: softmax stats (l15 shuffles + cross-wave LDS reduce) ----
  float m[4], l[4];
#pragma unroll
  for (int r = 0; r < 4; r++) m[r] = -1e30f;
#pragma unroll
  for (int st = 0; st < 32; st++)
#pragma unroll
    for (int r = 0; r < 4; r++) m[r] = fmaxf(m[r], acc[st][r]);
#pragma unroll
  for (int off = 1; off < 16; off <<= 1)
#pragma unroll
    for (int r = 0; r < 4; r++) m[r] = fmaxf(m[r], __shfl_xor(m[r], off, 64));
  if (l15 == 0)
#pragma unroll
    for (int r = 0; r < 4; r++) red[rg * 64 + cgi * 16 + quad * 4 + r] = m[r];
  __syncthreads();
#pragma unroll
  for (int r = 0; r < 4; r++) {
    int row = rg * 64 + quad * 4 + r;
    float mm = red[row];
    for (int ww = 1; ww < 4; ww++) mm = fmaxf(mm, red[row + ww * 16]);
    m[r] = mm;
  }
#pragma unroll
  for (int r = 0; r < 4; r++) l[r] = 0.f;
#pragma unroll
  for (int st = 0; st < 32; st++)
#pragma unroll
    for (int r = 0; r < 4; r++) {
      float p = __expf(acc[st][r] - m[r]);
      acc[st][r] = p;   // unnormalized exp kept in regs
      l[r] += p;
    }
#pragma unroll
  for (int off = 1; off < 16; off <<= 1)
#pragma unroll
    for (int r = 0; r < 4; r++) l[r] += __shfl_xor(l[r], off, 64);
  if (l15 == 0)
#pragma unroll
    for (int r = 0; r < 4; r++) red[256 + rg * 64 + cgi * 16 + quad * 4 + r] = l[r];
  __syncthreads();
#pragma unroll
  for (int r = 0; r < 4; r++) {
    int row = 256 + rg * 64 + quad * 4 + r;
    float s_ = 0.f;
    for (int ww = 0; ww < 4; ww++) s_ += red[row + ww * 16];
    l[r] = 1.0f / s_;
  }

  // ---- phase 3: O = P V with normalize+attn-store interleaved (R4) ----
  f32x4v acc2[2][4];
#pragma unroll
  for (int hg = 0; hg < 2; hg++)
#pragma unroll
    for (int j = 0; j < 4; j++) acc2[hg][j] = (f32x4v){0.f, 0.f, 0.f, 0.f};
  const bf16* Vfb = Vf + (size_t)b * (1 << 20);  // 2 MB/batch, frag-packed
  const int w4 = w * 4;
  float* attn_base = attn + ((size_t)(b * 2048) + q0 + rg * 16 + quad * 4) * 2048 +
                     cgi * 16 + l15;

  // prologue: normalize st=0, store attn row-chunk 0, write Pst[0], preload V(0)
#pragma unroll
  for (int r = 0; r < 4; r++) {
    float p = acc[0][r] * l[r];
    attn_base[(size_t)r * 2048] = p;
    Pst[0][rg * 16 + quad * 4 + r][cgi * 16 + l15] = (bf16)p;
  }
  bf16x8v vfp[2][2][4];
#pragma unroll
  for (int ss = 0; ss < 2; ss++)
#pragma unroll
    for (int j = 0; j < 4; j++)
      vfp[0][ss][j] = *(const bf16x8v*)(Vfb + ((size_t)(w4 + j) * 64 + ss) * 512 + lane8);

#pragma unroll
  for (int st = 0; st < 32; ++st) {
    const int cur = st & 1;
    WAIT_LGKM_0;  // my Pst writes (st) and prior pb reads (st-1) retired
    BARRIER;      // publish P(st); licenses overwrite of buf cur^1
    const char* pb = (const char*)Pst[cur];
    bf16x8v a0[2], a1[2];
#pragma unroll
    for (int ss = 0; ss < 2; ss++) {
      a0[ss] = *(const bf16x8v*)(pb + l15 * 144 + ss * 64 + quad * 16);
      a1[ss] = *(const bf16x8v*)(pb + (16 + l15) * 144 + ss * 64 + quad * 16);
    }
    if (st < 31) {
      // normalize + attn store + Pst write for st+1 (spreads the 134 MB write)
#pragma unroll
      for (int r = 0; r < 4; r++) {
        float p = acc[st + 1][r] * l[r];
        attn_base[(size_t)r * 2048 + (st + 1) * 64] = p;
        Pst[cur ^ 1][rg * 16 + quad * 4 + r][cgi * 16 + l15] = (bf16)p;
      }
      // ping-pong V prefetch for st+1 (covered by the MFMA block below)
#pragma unroll
      for (int ss = 0; ss < 2; ss++)
#pragma unroll
        for (int j = 0; j < 4; j++)
          vfp[cur ^ 1][ss][j] = *(const bf16x8v*)(
              Vfb + ((size_t)(w4 + j) * 64 + (st + 1) * 2 + ss) * 512 + lane8);
    }
#pragma unroll
    for (int ss = 0; ss < 2; ss++)
#pragma unroll
      for (int j = 0; j < 4; j++) {
        acc2[0][j] = MFMA(a0[ss], vfp[cur][ss][j], acc2[0][j]);
        acc2[1][j] = MFMA(a1[ss], vfp[cur][ss][j], acc2[1][j]);
      }
  }

  // ---- epilogue A: stage O-tile (bf16, XOR-swizzled) into Os;
  //      prefetch first Wpf frags before the barrier ----
#pragma unroll
  for (int hg = 0; hg < 2; hg++)
#pragma unroll
    for (int j = 0; j < 4; j++) {
      const int colb = (w * 64 + j * 16 + l15) * 2;
#pragma unroll
      for (int r = 0; r < 4; r++) {
        const int row = hg * 16 + quad * 4 + r;
        *(bf16*)((char*)Os + row * 1024 + (colb ^ ((row & 7) << 4))) =
            (bf16)acc2[hg][j][r];
      }
    }
  bf16x8v bfq[2][4];
#pragma unroll
  for (int j2 = 0; j2 < 4; j2++)
    bfq[0][j2] = *(const bf16x8v*)(Wpf + ((size_t)(w4 + j2) * 16 + 0) * 512 + lane8);
  WAIT_LGKM_0;
  BARRIER;

  // ---- epilogue B: out = O @ Wp (+bp) + x residual, LayerNorm, write Y ----
  f32x4v pacc[2][4];
#pragma unroll
  for (int rt = 0; rt < 2; rt++)
#pragma unroll
    for (int j2 = 0; j2 < 4; j2++) pacc[rt][j2] = (f32x4v){0.f, 0.f, 0.f, 0.f};
  const int sx7e = l15 & 7;
#pragma unroll
  for (int kk = 0; kk < 16; ++kk) {
    if (kk < 15) {
#pragma unroll
      for (int j2 = 0; j2 < 4; j2++)
        bfq[(kk + 1) & 1][j2] =
            *(const bf16x8v*)(Wpf + ((size_t)(w4 + j2) * 16 + kk + 1) * 512 + lane8);
    }
    const int swz = (((kk * 4 + quad) ^ sx7e) << 4);
    bf16x8v af0 = *(const bf16x8v*)((const char*)Os + l15 * 1024 + swz);
    bf16x8v af1 = *(const bf16x8v*)((const char*)Os + (16 + l15) * 1024 + swz);
#pragma unroll
    for (int j2 = 0; j2 < 4; j2++) {
      pacc[0][j2] = MFMA(af0, bfq[kk & 1][j2], pacc[0][j2]);
      pacc[1][j2] = MFMA(af1, bfq[kk & 1][j2], pacc[1][j2]);
    }
  }

  const float* xr = x + ((size_t)b * 2048 + q0) * 512;
  float s1[2][4], s2[2][4];
#pragma unroll
  for (int rt = 0; rt < 2; rt++)
#pragma unroll
    for (int r = 0; r < 4; r++) { s1[rt][r] = 0.f; s2[rt][r] = 0.f; }
#pragma unroll
  for (int rt = 0; rt < 2; rt++)
#pragma unroll
    for (int j2 = 0; j2 < 4; j2++) {
      const int col = w * 64 + j2 * 16 + l15;
      const float bpv = bp[col];
#pragma unroll
      for (int r = 0; r < 4; r++) {
        const int row = rt * 16 + quad * 4 + r;
        float v = pacc[rt][j2][r] + bpv + xr[(size_t)row * 512 + col];
        pacc[rt][j2][r] = v;
        s1[rt][r] += v;
        s2[rt][r] += v * v;
      }
    }
#pragma unroll
  for (int off = 1; off < 16; off <<= 1)
#pragma unroll
    for (int rt = 0; rt < 2; rt++)
#pragma unroll
      for (int r = 0; r < 4; r++) {
        s1[rt][r] += __shfl_xor(s1[rt][r], off, 64);
        s2[rt][r] += __shfl_xor(s2[rt][r], off, 64);
      }
  if (l15 == 0)
#pragma unroll
    for (int rt = 0; rt < 2; rt++)
#pragma unroll
      for (int r = 0; r < 4; r++) {
        red[w * 32 + rt * 16 + quad * 4 + r] = s1[rt][r];
        red[256 + w * 32 + rt * 16 + quad * 4 + r] = s2[rt][r];
      }
  __syncthreads();
  float mu[2][4], rs[2][4];
#pragma unroll
  for (int rt = 0; rt < 2; rt++)
#pragma unroll
    for (int r = 0; r < 4; r++) {
      const int row = rt * 16 + quad * 4 + r;
      float a1 = 0.f, a2 = 0.f;
      for (int ww = 0; ww < 8; ww++) {
        a1 += red[ww * 32 + row];
        a2 += red[256 + ww * 32 + row];
      }
      mu[rt][r] = a1 * (1.0f / 512.0f);
      float var = a2 * (1.0f / 512.0f) - mu[rt][r] * mu[rt][r];
      rs[rt][r] = rsqrtf(var + 1e-5f);
    }
  float* Yr = Y + ((size_t)b * 2048 + q0) * 512;
#pragma unroll
  for (int rt = 0; rt < 2; rt++)
#pragma unroll
    for (int j2 = 0; j2 < 4; j2++) {
      const int col = w * 64 + j2 * 16 + l15;
      const float g = gamma[col], be = beta[col];
#pragma unroll
      for (int r = 0; r < 4; r++) {
        const int row = rt * 16 + quad * 4 + r;
        Yr[(size_t)row * 512 + col] = (pacc[rt][j2][r] - mu[rt][r]) * rs[rt][r] * g + be;
      }
    }
}

// ---------------------------------------------------------------------------
extern "C" void kernel_launch(void* const* d_in, const int* in_sizes, int n_in,
                              void* d_out, int out_size, void* d_ws, size_t ws_size,
                              hipStream_t stream) {
  const float* x = (const float*)d_in[0];
  const float* Wq = (const float*)d_in[1];
  const float* bq = (const float*)d_in[2];
  const float* Wk = (const float*)d_in[3];
  const float* bk = (const float*)d_in[4];
  const float* Wv = (const float*)d_in[5];
  const float* bv = (const float*)d_in[6];
  const float* Wp = (const float*)d_in[7];
  const float* bp = (const float*)d_in[8];
  const float* gamma = (const float*)d_in[9];
  const float* beta = (const float*)d_in[10];

  char* ws = (char*)d_ws;
  bf16* WT = (bf16*)ws;                                      // 2 MB
  size_t off = 4ull * 512 * 512 * 2;
  bf16* Qd = (bf16*)(ws + off); off += 16384ull * 512 * 2;   // 16 MB
  bf16* Kfd = (bf16*)(ws + off); off += 16384ull * 512 * 2;  // 16 MB (frag-packed K)
  bf16* Vfd = (bf16*)(ws + off); off += 16384ull * 512 * 2;  // 16 MB (frag-packed V)
  bf16* Wpf = (bf16*)(ws + off); off += 512ull * 1024;       // 0.5 MB (frag-packed Wp)

  float* Y = (float*)d_out;                     // f32 [8][2048][512]
  float* attn = Y + 8ull * 2048 * 512;          // f32 [8][2048][2048]
  bf16* Xb = (bf16*)d_out;  // bf16 X parked in Y region (consumed by qkv_gemm)

  hipLaunchKernelGGL(prep, dim3(2048), dim3(1024), 0, stream,
                     Wq, Wk, Wv, Wp, x, WT, Wpf, Xb);
  hipLaunchKernelGGL(qkv_gemm, dim3(4, 128, 3), dim3(256), 0, stream,
                     Xb, WT, bq, bk, bv, Qd, Kfd, Vfd);
  hipLaunchKernelGGL(attn_kernel, dim3(512), dim3(512), 0, stream,
                     Qd, Kfd, Vfd, attn, Wpf, bp, x, gamma, beta, Y);
}